// Round 8
// baseline (1587.382 us; speedup 1.0000x reference)
//
#include <hip/hip_runtime.h>
#include <cmath>

constexpr int NN   = 100000;
constexpr int FIN  = 128;
constexpr int HH   = 64;
constexpr int NE   = 3200000;
constexpr int NFB  = (NN + 127) / 128;   // 782 buckets of 128 nodes
constexpr int PCAP2 = 4608;              // per-bucket capacity (mean 4092, sigma~64)

typedef __attribute__((ext_vector_type(8))) short short8;
typedef __attribute__((ext_vector_type(4))) float f32x4;

// bf16 round-to-nearest-even split helpers
__device__ __forceinline__ ushort f2bf(float x) {
    unsigned u = __float_as_uint(x);
    u += 0x7FFF + ((u >> 16) & 1);
    return (ushort)(u >> 16);
}
__device__ __forceinline__ float bf2f(ushort h) {
    return __uint_as_float(((unsigned)h) << 16);
}
__device__ __forceinline__ unsigned pack2(float a, float b) {
    return (unsigned)f2bf(a) | ((unsigned)f2bf(b) << 16);
}

// ---------------- edge partition: 782 buckets of 128 nodes ----------------
// 8192 edges/WG. LDS per-bucket count -> one global atomicAdd per (WG,bucket)
// reserves a chunk -> scatter PACKED edges ((src<<7)|(tgt&127), 4 B).
__global__ void __launch_bounds__(256) k_part(const int* __restrict__ ei,
                                              int* __restrict__ gcnt,
                                              int* __restrict__ pairs) {
    __shared__ int lcnt[NFB];
    __shared__ int lbase[NFB];
    int t = threadIdx.x;
    for (int i = t; i < NFB; i += 256) lcnt[i] = 0;
    __syncthreads();

    long long base = (long long)blockIdx.x * 8192;
    int4 r4[8], c4[8];
    int nv[8];
#pragma unroll
    for (int s = 0; s < 8; ++s) {
        long long e = base + s * 1024 + t * 4;
        if (e < NE) {
            r4[s] = ((const int4*)(ei))[e >> 2];
            c4[s] = ((const int4*)(ei + NE))[e >> 2];
            nv[s] = 1;
            atomicAdd(&lcnt[c4[s].x >> 7], 1);
            atomicAdd(&lcnt[c4[s].y >> 7], 1);
            atomicAdd(&lcnt[c4[s].z >> 7], 1);
            atomicAdd(&lcnt[c4[s].w >> 7], 1);
        } else {
            nv[s] = 0;
        }
    }
    __syncthreads();
    for (int i = t; i < NFB; i += 256) {
        int c = lcnt[i];
        lbase[i] = c ? atomicAdd(&gcnt[i], c) : 0;
        lcnt[i] = 0;  // reuse as cursor
    }
    __syncthreads();
#pragma unroll
    for (int s = 0; s < 8; ++s) {
        if (!nv[s]) continue;
        int rr[4] = {r4[s].x, r4[s].y, r4[s].z, r4[s].w};
        int cc[4] = {c4[s].x, c4[s].y, c4[s].z, c4[s].w};
#pragma unroll
        for (int k = 0; k < 4; ++k) {
            int b   = cc[k] >> 7;
            int p   = atomicAdd(&lcnt[b], 1);
            int pos = lbase[b] + p;
            if (pos < PCAP2) pairs[b * PCAP2 + pos] = (rr[k] << 7) | (cc[k] & 127);
        }
    }
}

// per-bucket degree histogram -> dis only (deg/rowptr/csr no longer exist)
__global__ void __launch_bounds__(256) k_deg(const int* __restrict__ pairs,
                                             const int* __restrict__ gcnt,
                                             float* __restrict__ dis) {
    __shared__ int h[128];
    int b = blockIdx.x, t = threadIdx.x;
    if (t < 128) h[t] = 0;
    __syncthreads();
    int cnt = min(gcnt[b], PCAP2);
    const int* pb = pairs + (size_t)b * PCAP2;
    for (int i = t; i < cnt; i += 256) atomicAdd(&h[pb[i] & 127], 1);
    __syncthreads();
    int n = b * 128 + t;
    if (t < 128 && n < NN) dis[n] = rsqrtf((float)(h[t] + 1));
}

// xt v6 (MFMA) = bf16(dis ⊙ (x @ W_gcn)). Proven round-4 version, unchanged.
__global__ void __launch_bounds__(256) k_xt(const float* __restrict__ x,
                                            const ushort* __restrict__ wgx,
                                            const float* __restrict__ dis,
                                            ushort* __restrict__ xtb) {
    __shared__ ushort Ahi[64 * 136];   // 17408 B
    __shared__ ushort Alo[64 * 136];   // 17408 B (reused for output staging)
    __shared__ float sdis[64];
    const ushort* GXhi = wgx;              // [64 cols][128 k]
    const ushort* GXlo = wgx + 64 * 128;
    int t  = threadIdx.x;
    int r0 = blockIdx.x * 64;
    if (t < 64) sdis[t] = (r0 + t < NN) ? dis[r0 + t] : 0.f;
    unsigned* Ahi32 = (unsigned*)Ahi;
    unsigned* Alo32 = (unsigned*)Alo;
#pragma unroll
    for (int s = 0; s < 8; ++s) {
        int idx = t + 256 * s;      // 2048 float4 slots = 64 rows x 32
        int nd  = idx >> 5;         // row 0..63
        int kq  = idx & 31;         // float4 within 128-col row
        bool ok = (r0 + nd) < NN;
        float4 v = ok ? ((const float4*)(x + (size_t)(r0 + nd) * FIN))[kq]
                      : make_float4(0.f, 0.f, 0.f, 0.f);
        int b2 = nd * 68 + kq * 2;
        float hx = bf2f(f2bf(v.x)), hy = bf2f(f2bf(v.y));
        float hz = bf2f(f2bf(v.z)), hw = bf2f(f2bf(v.w));
        Ahi32[b2]     = pack2(v.x, v.y);
        Ahi32[b2 + 1] = pack2(v.z, v.w);
        Alo32[b2]     = pack2(v.x - hx, v.y - hy);
        Alo32[b2 + 1] = pack2(v.z - hz, v.w - hw);
    }
    __syncthreads();

    int lane = t & 63, w = t >> 6, l15 = lane & 15;
    int kbase = (lane >> 4) * 8;
    int j = w * 16 + l15;          // output col
    f32x4 acc[4];
#pragma unroll
    for (int m = 0; m < 4; ++m) acc[m] = (f32x4){0.f, 0.f, 0.f, 0.f};
    short8 bh[4], bl[4];
#pragma unroll
    for (int ks = 0; ks < 4; ++ks) {
        bh[ks] = *(const short8*)(GXhi + j * 128 + ks * 32 + kbase);
        bl[ks] = *(const short8*)(GXlo + j * 128 + ks * 32 + kbase);
    }
#pragma unroll
    for (int mt = 0; mt < 4; ++mt) {
        int abase = (mt * 16 + l15) * 136 + kbase;
#pragma unroll
        for (int ks = 0; ks < 4; ++ks) {
            short8 ah = *(const short8*)&Ahi[abase + ks * 32];
            short8 al = *(const short8*)&Alo[abase + ks * 32];
            acc[mt] = __builtin_amdgcn_mfma_f32_16x16x32_bf16(ah, bh[ks], acc[mt], 0, 0, 0);
            acc[mt] = __builtin_amdgcn_mfma_f32_16x16x32_bf16(al, bh[ks], acc[mt], 0, 0, 0);
            acc[mt] = __builtin_amdgcn_mfma_f32_16x16x32_bf16(ah, bl[ks], acc[mt], 0, 0, 0);
        }
    }
    __syncthreads();   // all reads of Ahi/Alo done
#pragma unroll
    for (int mt = 0; mt < 4; ++mt) {
#pragma unroll
        for (int reg = 0; reg < 4; ++reg) {
            int row = mt * 16 + (lane >> 4) * 4 + reg;
            Alo[row * 64 + j] = f2bf(sdis[row] * acc[mt][reg]);
        }
    }
    __syncthreads();
    const uint4* src = (const uint4*)Alo;
    uint4* dst = (uint4*)(xtb + (size_t)r0 * HH);
#pragma unroll
    for (int s = 0; s < 2; ++s) {
        int u   = t + 256 * s;
        int row = u >> 3;
        if (r0 + row < NN) dst[u] = src[u];
    }
}

// gacc: CSR-free gather. One block per 128-node bucket; acc[128][68] fp32 in
// LDS (padded stride 68 -> spread banks); 8 waves each scan 1/8 of the
// bucket's unsorted pairs, 8 lanes/edge x 16 B xt row, ds_add_f32 accumulate.
// Epilogue: self term + bias + relu -> gbuf (coalesced).
__global__ void __launch_bounds__(512) k_gacc(const int* __restrict__ pairs,
                                              const int* __restrict__ gcnt,
                                              const float* __restrict__ dis,
                                              const ushort* __restrict__ xtb,
                                              const float* __restrict__ bg,
                                              float* __restrict__ gbuf) {
    __shared__ float accf[128 * 68];   // 34816 B
    int b = blockIdx.x;
    int t = threadIdx.x;
    for (int i = t; i < 128 * 68; i += 512) accf[i] = 0.f;
    __syncthreads();

    int cnt = min(gcnt[b], PCAP2);
    const int* pb = pairs + (size_t)b * PCAP2;
    int w    = t >> 6;          // wave 0..7
    int lane = t & 63;
    int r    = lane >> 3;       // edge slot 0..7
    int q    = lane & 7;        // feature octet

    int chunk  = (cnt + 7) >> 3;
    int wstart = w * chunk;
    int wend   = min(wstart + chunk, cnt);
    for (int i = wstart + r; i < wend; i += 8) {
        int p   = pb[i];                       // 8 lanes/group share one addr
        int src = p >> 7;
        int tl  = p & 127;
        short8 v = ((const short8*)(xtb + (size_t)src * HH))[q];
        float* ar = &accf[tl * 68 + q * 8];
#pragma unroll
        for (int j = 0; j < 8; ++j) atomicAdd(&ar[j], bf2f((ushort)v[j]));
    }
    __syncthreads();

    // epilogue: 128 nodes x 8 octets = 1024 slots over 512 threads
#pragma unroll
    for (int s = 0; s < 2; ++s) {
        int slot = t + 512 * s;
        int nd   = slot >> 3;
        int qq   = slot & 7;
        int n    = b * 128 + nd;
        if (n < NN) {
            float dn  = dis[n];
            short8 xs = ((const short8*)(xtb + (size_t)n * HH))[qq];
            float4 b0 = ((const float4*)bg)[qq * 2];
            float4 b1 = ((const float4*)bg)[qq * 2 + 1];
            float bb[8] = {b0.x, b0.y, b0.z, b0.w, b1.x, b1.y, b1.z, b1.w};
            const float* ar = &accf[nd * 68 + qq * 8];
            float res[8];
#pragma unroll
            for (int j = 0; j < 8; ++j)
                res[j] = fmaxf(fmaf(dn, ar[j] + bf2f((ushort)xs[j]), bb[j]), 0.f);
            float4* go = (float4*)(gbuf + (size_t)n * HH + qq * 8);
            go[0] = make_float4(res[0], res[1], res[2], res[3]);
            go[1] = make_float4(res[4], res[5], res[6], res[7]);
        }
    }
}

// Prep: split GRU weights AND W_gcn^T into bf16 hi/lo, fused layouts.
__global__ void k_wprep(const float* __restrict__ Wih, const float* __restrict__ Whh,
                        const float* __restrict__ Wg, ushort* __restrict__ bsp) {
    ushort* Bhi  = bsp;
    ushort* Blo  = bsp + 192 * 128;
    ushort* BShi = bsp + 2 * 192 * 128;
    ushort* BSlo = BShi + 64 * 64;
    ushort* GXhi = BSlo + 64 * 64;       // [64 cols][128 k] = W_gcn^T
    ushort* GXlo = GXhi + 64 * 128;
    int i = blockIdx.x * 256 + threadIdx.x;
    if (i < 192 * 128) {
        int j = i >> 7, k = i & 127;
        float wv = (k < 64) ? Wih[j * 64 + k] : Whh[j * 64 + (k - 64)];
        ushort hi = f2bf(wv);
        Bhi[i] = hi;
        Blo[i] = f2bf(wv - bf2f(hi));
    }
    if (i < 64 * 64) {
        int j = i >> 6, k = i & 63;
        float wv = Whh[(128 + j) * 64 + k];
        ushort hi = f2bf(wv);
        BShi[i] = hi;
        BSlo[i] = f2bf(wv - bf2f(hi));
    }
    if (i < 64 * 128) {
        int j = i >> 7, k = i & 127;
        float wv = Wg[k * HH + j];
        ushort hi = f2bf(wv);
        GXhi[i] = hi;
        GXlo[i] = f2bf(wv - bf2f(hi));
    }
}

// GRU v8 (MFMA): block = 32 nodes, 4 waves. Proven round-6 version, unchanged.
__global__ void __launch_bounds__(256) k_gru(
    const float* __restrict__ gbuf, const float* __restrict__ hprev,
    const ushort* __restrict__ bsp,
    const float* __restrict__ bih, const float* __restrict__ bhh,
    float* __restrict__ out) {
    __shared__ ushort Ahi[32 * 136];   // 8704 B
    __shared__ ushort Alo[32 * 136];   // 8704 B
    const ushort* Bhi  = bsp;
    const ushort* Blo  = bsp + 192 * 128;
    const ushort* BShi = bsp + 2 * 192 * 128;
    const ushort* BSlo = BShi + 64 * 64;

    int t  = threadIdx.x;
    int n0 = blockIdx.x * 32;

    unsigned* Ahi32 = (unsigned*)Ahi;
    unsigned* Alo32 = (unsigned*)Alo;
#pragma unroll
    for (int s = 0; s < 2; ++s) {
        int idx = t + 256 * s;           // 0..511 float4 slots
        int nd  = idx >> 4;              // node 0..31
        int kq  = idx & 15;              // float4 within row
        bool ok = (n0 + nd) < NN;
        float4 vg = ok ? ((const float4*)(gbuf  + (size_t)(n0 + nd) * HH))[kq]
                       : make_float4(0.f, 0.f, 0.f, 0.f);
        float4 vh = ok ? ((const float4*)(hprev + (size_t)(n0 + nd) * HH))[kq]
                       : make_float4(0.f, 0.f, 0.f, 0.f);
        int bg2 = nd * 68 + kq * 2;      // uint index, g part
        int bh2 = bg2 + 32;              // h part
        float ghx = bf2f(f2bf(vg.x)), ghy = bf2f(f2bf(vg.y));
        float ghz = bf2f(f2bf(vg.z)), ghw = bf2f(f2bf(vg.w));
        float hhx = bf2f(f2bf(vh.x)), hhy = bf2f(f2bf(vh.y));
        float hhz = bf2f(f2bf(vh.z)), hhw = bf2f(f2bf(vh.w));
        Ahi32[bg2]     = pack2(vg.x, vg.y);
        Ahi32[bg2 + 1] = pack2(vg.z, vg.w);
        Alo32[bg2]     = pack2(vg.x - ghx, vg.y - ghy);
        Alo32[bg2 + 1] = pack2(vg.z - ghz, vg.w - ghw);
        Ahi32[bh2]     = pack2(vh.x, vh.y);
        Ahi32[bh2 + 1] = pack2(vh.z, vh.w);
        Alo32[bh2]     = pack2(vh.x - hhx, vh.y - hhy);
        Alo32[bh2 + 1] = pack2(vh.z - hhz, vh.w - hhw);
    }
    __syncthreads();

    int lane  = t & 63;
    int w     = t >> 6;              // wave = j-group
    int l15   = lane & 15;
    int kbase = (lane >> 4) * 8;     // K sub-block per mfma fragment

    f32x4 acc[4][2];
#pragma unroll
    for (int a = 0; a < 4; ++a)
#pragma unroll
        for (int m = 0; m < 2; ++m) acc[a][m] = (f32x4){0.f, 0.f, 0.f, 0.f};

#pragma unroll
    for (int g = 0; g < 3; ++g) {
        int brow = (w + 4 * g) * 16 + l15;
        short8 bh[4], bl[4];
#pragma unroll
        for (int ks = 0; ks < 4; ++ks) {
            bh[ks] = *(const short8*)(Bhi + brow * 128 + ks * 32 + kbase);
            bl[ks] = *(const short8*)(Blo + brow * 128 + ks * 32 + kbase);
        }
#pragma unroll
        for (int mt = 0; mt < 2; ++mt) {
            int abase = (mt * 16 + l15) * 136 + kbase;
#pragma unroll
            for (int ks = 0; ks < 4; ++ks) {
                short8 ah = *(const short8*)&Ahi[abase + ks * 32];
                short8 al = *(const short8*)&Alo[abase + ks * 32];
                acc[g][mt] = __builtin_amdgcn_mfma_f32_16x16x32_bf16(ah, bh[ks], acc[g][mt], 0, 0, 0);
                acc[g][mt] = __builtin_amdgcn_mfma_f32_16x16x32_bf16(al, bh[ks], acc[g][mt], 0, 0, 0);
                acc[g][mt] = __builtin_amdgcn_mfma_f32_16x16x32_bf16(ah, bl[ks], acc[g][mt], 0, 0, 0);
            }
        }
    }
    {
        int brow = w * 16 + l15;
        short8 bh[2], bl[2];
#pragma unroll
        for (int ks = 0; ks < 2; ++ks) {
            bh[ks] = *(const short8*)(BShi + brow * 64 + ks * 32 + kbase);
            bl[ks] = *(const short8*)(BSlo + brow * 64 + ks * 32 + kbase);
        }
#pragma unroll
        for (int mt = 0; mt < 2; ++mt) {
            int abase = (mt * 16 + l15) * 136 + 64 + kbase;
#pragma unroll
            for (int ks = 0; ks < 2; ++ks) {
                short8 ah = *(const short8*)&Ahi[abase + ks * 32];
                short8 al = *(const short8*)&Alo[abase + ks * 32];
                acc[3][mt] = __builtin_amdgcn_mfma_f32_16x16x32_bf16(ah, bh[ks], acc[3][mt], 0, 0, 0);
                acc[3][mt] = __builtin_amdgcn_mfma_f32_16x16x32_bf16(al, bh[ks], acc[3][mt], 0, 0, 0);
                acc[3][mt] = __builtin_amdgcn_mfma_f32_16x16x32_bf16(ah, bl[ks], acc[3][mt], 0, 0, 0);
            }
        }
    }

    int j = 16 * w + l15;
    float br  = bih[j] + bhh[j];
    float bz  = bih[HH + j] + bhh[HH + j];
    float bin = bih[2 * HH + j];
    float bhn = bhh[2 * HH + j];
#pragma unroll
    for (int mt = 0; mt < 2; ++mt) {
#pragma unroll
        for (int reg = 0; reg < 4; ++reg) {
            int row  = mt * 16 + (lane >> 4) * 4 + reg;
            int node = n0 + row;
            if (node < NN) {
                float S1 = acc[0][mt][reg];
                float S2 = acc[1][mt][reg];
                float S3 = acc[2][mt][reg];   // i_n + h_n
                float Hn = acc[3][mt][reg];   // h_n
                float r  = __builtin_amdgcn_rcpf(1.f + __expf(-(S1 + br)));
                float z  = __builtin_amdgcn_rcpf(1.f + __expf(-(S2 + bz)));
                float na = (S3 - Hn + bin) + r * (Hn + bhn);
                float e2 = __expf(2.f * na);
                float nv = fmaf(-2.f, __builtin_amdgcn_rcpf(1.f + e2), 1.f);  // tanh
                int lidx = row * 136 + 64 + j;
                float h  = bf2f(Ahi[lidx]) + bf2f(Alo[lidx]);  // hprev
                float o  = (1.f - z) * nv + z * h;
                out[(size_t)node * HH + j] = o;
                out[(size_t)NN * HH + (size_t)node * HH + j] = o;
            }
        }
    }
}

extern "C" void kernel_launch(void* const* d_in, const int* in_sizes, int n_in,
                              void* d_out, int out_size, void* d_ws, size_t ws_size,
                              hipStream_t stream) {
    const float* x   = (const float*)d_in[0];
    const int*   ei  = (const int*)d_in[1];
    const float* hs  = (const float*)d_in[2];
    const float* Wg  = (const float*)d_in[3];
    const float* bg  = (const float*)d_in[4];
    const float* Wih = (const float*)d_in[5];
    const float* Whh = (const float*)d_in[6];
    const float* bih = (const float*)d_in[7];
    const float* bhh = (const float*)d_in[8];
    float* out = (float*)d_out;

    char* ws = (char*)d_ws;
    int*    pairs  = (int*)   (ws);                // 782*4608*4 = 14,413,824 B
    ushort* xtb    = (ushort*)(ws + 14500000);     // 12,800,000 B
    float*  gbuf   = (float*) (ws + 27400000);     // 25,600,000 B
    float*  dis    = (float*) (ws + 53000000);     //    400,000 B
    ushort* wsplit = (ushort*)(ws + 53400000);     //    147,456 B
    int*    gcnt   = (int*)   (ws + 53600000);     //      3,128 B

    hipMemsetAsync(gcnt, 0, NFB * sizeof(int), stream);

    hipLaunchKernelGGL(k_wprep, dim3(96), dim3(256), 0, stream, Wih, Whh, Wg, wsplit);
    hipLaunchKernelGGL(k_part,  dim3((NE + 8191) / 8192), dim3(256), 0, stream, ei, gcnt, pairs);
    hipLaunchKernelGGL(k_deg,   dim3(NFB), dim3(256), 0, stream, pairs, gcnt, dis);
    hipLaunchKernelGGL(k_xt,    dim3((NN + 63) / 64), dim3(256), 0, stream,
                       x, wsplit + 2 * 192 * 128 + 2 * 64 * 64, dis, xtb);
    hipLaunchKernelGGL(k_gacc,  dim3(NFB), dim3(512), 0, stream,
                       pairs, gcnt, dis, xtb, bg, gbuf);
    hipLaunchKernelGGL(k_gru,   dim3((NN + 31) / 32), dim3(256), 0, stream,
                       gbuf, hs, wsplit, bih, bhh, out);
}

// Round 9
// 309.247 us; speedup vs baseline: 5.1331x; 5.1331x over previous
//
#include <hip/hip_runtime.h>
#include <cmath>

constexpr int NN  = 100000;
constexpr int FIN = 128;
constexpr int HH  = 64;
constexpr int NE  = 3200000;
constexpr int NB  = (NN + 255) / 256;  // 391 = fine buckets of 256 nodes
constexpr int NFB  = NB;               // fine bucket count (== NB)
constexpr int PCAP = 10240;            // per-bucket capacity (mean 8184, sigma~90)

typedef __attribute__((ext_vector_type(8))) short short8;
typedef __attribute__((ext_vector_type(4))) float f32x4;

// bf16 round-to-nearest-even split helpers
__device__ __forceinline__ ushort f2bf(float x) {
    unsigned u = __float_as_uint(x);
    u += 0x7FFF + ((u >> 16) & 1);
    return (ushort)(u >> 16);
}
__device__ __forceinline__ float bf2f(ushort h) {
    return __uint_as_float(((unsigned)h) << 16);
}
__device__ __forceinline__ unsigned pack2(float a, float b) {
    return (unsigned)f2bf(a) | ((unsigned)f2bf(b) << 16);
}

// ---------------- edge partition: 391 buckets of 256 nodes ----------------
// 8192 edges/WG (measured-good). LDS per-bucket count -> one global atomicAdd
// per (WG,bucket) reserves a chunk -> scatter PACKED edges ((src<<8)|(tgt&255)).
__global__ void __launch_bounds__(256) k_part(const int* __restrict__ ei,
                                              int* __restrict__ gcnt,
                                              int* __restrict__ pairs) {
    __shared__ int lcnt[NFB];
    __shared__ int lbase[NFB];
    int t = threadIdx.x;
    for (int i = t; i < NFB; i += 256) lcnt[i] = 0;
    __syncthreads();

    long long base = (long long)blockIdx.x * 8192;
    int4 r4[8], c4[8];
    int nv[8];
#pragma unroll
    for (int s = 0; s < 8; ++s) {
        long long e = base + s * 1024 + t * 4;
        if (e < NE) {
            r4[s] = ((const int4*)(ei))[e >> 2];
            c4[s] = ((const int4*)(ei + NE))[e >> 2];
            nv[s] = 1;
            atomicAdd(&lcnt[c4[s].x >> 8], 1);
            atomicAdd(&lcnt[c4[s].y >> 8], 1);
            atomicAdd(&lcnt[c4[s].z >> 8], 1);
            atomicAdd(&lcnt[c4[s].w >> 8], 1);
        } else {
            nv[s] = 0;
        }
    }
    __syncthreads();
    for (int i = t; i < NFB; i += 256) {
        int c = lcnt[i];
        lbase[i] = c ? atomicAdd(&gcnt[i], c) : 0;
        lcnt[i] = 0;  // reuse as cursor
    }
    __syncthreads();
#pragma unroll
    for (int s = 0; s < 8; ++s) {
        if (!nv[s]) continue;
        int rr[4] = {r4[s].x, r4[s].y, r4[s].z, r4[s].w};
        int cc[4] = {c4[s].x, c4[s].y, c4[s].z, c4[s].w};
#pragma unroll
        for (int k = 0; k < 4; ++k) {
            int b   = cc[k] >> 8;
            int p   = atomicAdd(&lcnt[b], 1);
            int pos = lbase[b] + p;
            if (pos < PCAP) pairs[b * PCAP + pos] = (rr[k] << 8) | (cc[k] & 255);
        }
    }
}

// CSR build per bucket (512 threads: halved serial LDS chains vs 256).
// Entirely in LDS; emits deg / rowptr / dis / csr. Base offset via in-block
// masked reduce over gcnt[0..f). This exact variant passed in round-4 bench.
__global__ void __launch_bounds__(512) k_csr(const int* __restrict__ pairs,
                                             const int* __restrict__ gcnt,
                                             int* __restrict__ deg,
                                             int* __restrict__ rowptr,
                                             float* __restrict__ dis,
                                             int* __restrict__ csr) {
    __shared__ int sg[512];
    __shared__ int ldeg[256];
    __shared__ int lrp[512];
    __shared__ int lcur[256];
    __shared__ int lcsr[PCAP];  // 40 KB
    int f = blockIdx.x;
    int t = threadIdx.x;
    // exclusive prefix: base = sum(gcnt[0..f)), f <= 391 < 512
    sg[t] = (t < f) ? gcnt[t] : 0;
    if (t < 256) ldeg[t] = 0;
    __syncthreads();
    for (int off = 256; off > 0; off >>= 1) {
        if (t < off) sg[t] += sg[t + off];
        __syncthreads();
    }
    int base = sg[0];
    int cnt  = min(gcnt[f], PCAP);
    int n0   = f * 256;
    const int* pb = pairs + f * PCAP;
    for (int i = t; i < cnt; i += 512) atomicAdd(&ldeg[pb[i] & 255], 1);
    __syncthreads();
    int v = (t < 256) ? ldeg[t] : 0;
    lrp[t] = v;
    __syncthreads();
    for (int off = 1; off < 256; off <<= 1) {
        int add = (t >= off) ? lrp[t - off] : 0;
        __syncthreads();
        lrp[t] += add;
        __syncthreads();
    }
    int excl = lrp[t] - v;
    if (t < 256) {
        if (n0 + t < NN) {
            deg[n0 + t]    = v;
            rowptr[n0 + t] = base + excl;
            dis[n0 + t]    = rsqrtf((float)(v + 1));
        }
        lcur[t] = excl;
    }
    __syncthreads();
    for (int i = t; i < cnt; i += 512) {
        int e = pb[i];
        int p = atomicAdd(&lcur[e & 255], 1);
        lcsr[p] = e >> 8;
    }
    __syncthreads();
    for (int i = t; i < cnt; i += 512) csr[base + i] = lcsr[i];
}

// xt v6 (MFMA) = bf16(dis ⊙ (x @ W_gcn)). Proven round-4/5 version, unchanged.
__global__ void __launch_bounds__(256) k_xt(const float* __restrict__ x,
                                            const ushort* __restrict__ wgx,
                                            const float* __restrict__ dis,
                                            ushort* __restrict__ xtb) {
    __shared__ ushort Ahi[64 * 136];   // 17408 B
    __shared__ ushort Alo[64 * 136];   // 17408 B (reused for output staging)
    __shared__ float sdis[64];
    const ushort* GXhi = wgx;              // [64 cols][128 k]
    const ushort* GXlo = wgx + 64 * 128;
    int t  = threadIdx.x;
    int r0 = blockIdx.x * 64;
    if (t < 64) sdis[t] = (r0 + t < NN) ? dis[r0 + t] : 0.f;
    unsigned* Ahi32 = (unsigned*)Ahi;
    unsigned* Alo32 = (unsigned*)Alo;
#pragma unroll
    for (int s = 0; s < 8; ++s) {
        int idx = t + 256 * s;      // 2048 float4 slots = 64 rows x 32
        int nd  = idx >> 5;         // row 0..63
        int kq  = idx & 31;         // float4 within 128-col row
        bool ok = (r0 + nd) < NN;
        float4 v = ok ? ((const float4*)(x + (size_t)(r0 + nd) * FIN))[kq]
                      : make_float4(0.f, 0.f, 0.f, 0.f);
        int b2 = nd * 68 + kq * 2;
        float hx = bf2f(f2bf(v.x)), hy = bf2f(f2bf(v.y));
        float hz = bf2f(f2bf(v.z)), hw = bf2f(f2bf(v.w));
        Ahi32[b2]     = pack2(v.x, v.y);
        Ahi32[b2 + 1] = pack2(v.z, v.w);
        Alo32[b2]     = pack2(v.x - hx, v.y - hy);
        Alo32[b2 + 1] = pack2(v.z - hz, v.w - hw);
    }
    __syncthreads();

    int lane = t & 63, w = t >> 6, l15 = lane & 15;
    int kbase = (lane >> 4) * 8;
    int j = w * 16 + l15;          // output col
    f32x4 acc[4];
#pragma unroll
    for (int m = 0; m < 4; ++m) acc[m] = (f32x4){0.f, 0.f, 0.f, 0.f};
    short8 bh[4], bl[4];
#pragma unroll
    for (int ks = 0; ks < 4; ++ks) {
        bh[ks] = *(const short8*)(GXhi + j * 128 + ks * 32 + kbase);
        bl[ks] = *(const short8*)(GXlo + j * 128 + ks * 32 + kbase);
    }
#pragma unroll
    for (int mt = 0; mt < 4; ++mt) {
        int abase = (mt * 16 + l15) * 136 + kbase;
#pragma unroll
        for (int ks = 0; ks < 4; ++ks) {
            short8 ah = *(const short8*)&Ahi[abase + ks * 32];
            short8 al = *(const short8*)&Alo[abase + ks * 32];
            acc[mt] = __builtin_amdgcn_mfma_f32_16x16x32_bf16(ah, bh[ks], acc[mt], 0, 0, 0);
            acc[mt] = __builtin_amdgcn_mfma_f32_16x16x32_bf16(al, bh[ks], acc[mt], 0, 0, 0);
            acc[mt] = __builtin_amdgcn_mfma_f32_16x16x32_bf16(ah, bl[ks], acc[mt], 0, 0, 0);
        }
    }
    __syncthreads();   // all reads of Ahi/Alo done
#pragma unroll
    for (int mt = 0; mt < 4; ++mt) {
#pragma unroll
        for (int reg = 0; reg < 4; ++reg) {
            int row = mt * 16 + (lane >> 4) * 4 + reg;
            Alo[row * 64 + j] = f2bf(sdis[row] * acc[mt][reg]);
        }
    }
    __syncthreads();
    const uint4* src = (const uint4*)Alo;
    uint4* dst = (uint4*)(xtb + (size_t)r0 * HH);
#pragma unroll
    for (int s = 0; s < 2; ++s) {
        int u   = t + 256 * s;
        int row = u >> 3;
        if (r0 + row < NN) dst[u] = src[u];
    }
}

// gather v4: wave per node; 8 lanes/edge x 16 B, 2-edge unroll; pure
// accumulation (norm pre-folded into xtb); shfl_xor 8/16/32 reduce. Proven.
__global__ void __launch_bounds__(256) k_gather(const int* __restrict__ csr,
                                                const int* __restrict__ rowptr,
                                                const int* __restrict__ deg,
                                                const float* __restrict__ dis,
                                                const ushort* __restrict__ xtb,
                                                const float* __restrict__ bg,
                                                float* __restrict__ g) {
    __shared__ int lid[4][64];
    int t    = threadIdx.x;
    int lane = t & 63;
    int w    = t >> 6;
    int n    = blockIdx.x * 4 + w;   // grid = 25000*4 == NN exactly
    int r = lane >> 3;   // edge phase 0..7
    int q = lane & 7;    // feature octet (8 bf16 = 16 B)
    float acc[8] = {0.f, 0.f, 0.f, 0.f, 0.f, 0.f, 0.f, 0.f};
    float dn  = dis[n];
    int start = rowptr[n];
    int cnt   = deg[n];
    for (int c0 = 0; c0 < cnt; c0 += 64) {
        int m = min(64, cnt - c0);
        if (lane < m) lid[w][lane] = csr[start + c0 + lane];  // wave-synchronous
        int i = r;
        for (; i + 8 < m; i += 16) {
            int s0 = lid[w][i];
            int s1 = lid[w][i + 8];
            short8 v0 = ((const short8*)(xtb + (size_t)s0 * HH))[q];
            short8 v1 = ((const short8*)(xtb + (size_t)s1 * HH))[q];
#pragma unroll
            for (int j = 0; j < 8; ++j) acc[j] += bf2f((ushort)v0[j]);
#pragma unroll
            for (int j = 0; j < 8; ++j) acc[j] += bf2f((ushort)v1[j]);
        }
        if (i < m) {
            int s0 = lid[w][i];
            short8 v0 = ((const short8*)(xtb + (size_t)s0 * HH))[q];
#pragma unroll
            for (int j = 0; j < 8; ++j) acc[j] += bf2f((ushort)v0[j]);
        }
    }
#pragma unroll
    for (int j = 0; j < 8; ++j) {
        acc[j] += __shfl_xor(acc[j], 8, 64);
        acc[j] += __shfl_xor(acc[j], 16, 64);
        acc[j] += __shfl_xor(acc[j], 32, 64);
    }
    if (r == 0) {   // lanes 0..7 hold octet q
        short8 xs = ((const short8*)(xtb + (size_t)n * HH))[q];  // self term (pre-scaled)
        float4 b0 = ((const float4*)bg)[q * 2];
        float4 b1 = ((const float4*)bg)[q * 2 + 1];
        float bb[8] = {b0.x, b0.y, b0.z, b0.w, b1.x, b1.y, b1.z, b1.w};
        float res[8];
#pragma unroll
        for (int j = 0; j < 8; ++j)
            res[j] = fmaxf(fmaf(dn, acc[j] + bf2f((ushort)xs[j]), bb[j]), 0.f);
        float4* go = (float4*)(g + (size_t)n * HH + q * 8);
        go[0] = make_float4(res[0], res[1], res[2], res[3]);
        go[1] = make_float4(res[4], res[5], res[6], res[7]);
    }
}

// Prep: split GRU weights AND W_gcn^T into bf16 hi/lo; also zeroes gcnt
// (replaces the hipMemsetAsync launch; runs before k_part on the same stream).
__global__ void k_wprep(const float* __restrict__ Wih, const float* __restrict__ Whh,
                        const float* __restrict__ Wg, ushort* __restrict__ bsp,
                        int* __restrict__ gcnt) {
    ushort* Bhi  = bsp;
    ushort* Blo  = bsp + 192 * 128;
    ushort* BShi = bsp + 2 * 192 * 128;
    ushort* BSlo = BShi + 64 * 64;
    ushort* GXhi = BSlo + 64 * 64;       // [64 cols][128 k] = W_gcn^T
    ushort* GXlo = GXhi + 64 * 128;
    int i = blockIdx.x * 256 + threadIdx.x;
    if (i < NFB) gcnt[i] = 0;
    if (i < 192 * 128) {
        int j = i >> 7, k = i & 127;
        float wv = (k < 64) ? Wih[j * 64 + k] : Whh[j * 64 + (k - 64)];
        ushort hi = f2bf(wv);
        Bhi[i] = hi;
        Blo[i] = f2bf(wv - bf2f(hi));
    }
    if (i < 64 * 64) {
        int j = i >> 6, k = i & 63;
        float wv = Whh[(128 + j) * 64 + k];
        ushort hi = f2bf(wv);
        BShi[i] = hi;
        BSlo[i] = f2bf(wv - bf2f(hi));
    }
    if (i < 64 * 128) {
        int j = i >> 7, k = i & 127;
        float wv = Wg[k * HH + j];
        ushort hi = f2bf(wv);
        GXhi[i] = hi;
        GXlo[i] = f2bf(wv - bf2f(hi));
    }
}

// GRU v7 (MFMA): block = 64 nodes, 4 waves. Split-bf16 3-term MFMA GEMMs.
// (round-5 measured config: 68-70 µs, structure-invariant vs v8.)
__global__ void __launch_bounds__(256) k_gru(
    const float* __restrict__ gbuf, const float* __restrict__ hprev,
    const ushort* __restrict__ bsp,
    const float* __restrict__ bih, const float* __restrict__ bhh,
    float* __restrict__ out) {
    __shared__ ushort Ahi[64 * 136];   // 17408 B
    __shared__ ushort Alo[64 * 136];   // 17408 B
    const ushort* Bhi  = bsp;
    const ushort* Blo  = bsp + 192 * 128;
    const ushort* BShi = bsp + 2 * 192 * 128;
    const ushort* BSlo = BShi + 64 * 64;

    int t  = threadIdx.x;
    int n0 = blockIdx.x * 64;

    unsigned* Ahi32 = (unsigned*)Ahi;
    unsigned* Alo32 = (unsigned*)Alo;
#pragma unroll
    for (int s = 0; s < 4; ++s) {
        int idx = t + 256 * s;           // 0..1023 float4 slots
        int nd  = idx >> 4;              // node 0..63
        int kq  = idx & 15;              // float4 within row
        bool ok = (n0 + nd) < NN;
        float4 vg = ok ? ((const float4*)(gbuf  + (size_t)(n0 + nd) * HH))[kq]
                       : make_float4(0.f, 0.f, 0.f, 0.f);
        float4 vh = ok ? ((const float4*)(hprev + (size_t)(n0 + nd) * HH))[kq]
                       : make_float4(0.f, 0.f, 0.f, 0.f);
        int bg2 = nd * 68 + kq * 2;      // uint index, g part
        int bh2 = bg2 + 32;              // h part
        float ghx = bf2f(f2bf(vg.x)), ghy = bf2f(f2bf(vg.y));
        float ghz = bf2f(f2bf(vg.z)), ghw = bf2f(f2bf(vg.w));
        float hhx = bf2f(f2bf(vh.x)), hhy = bf2f(f2bf(vh.y));
        float hhz = bf2f(f2bf(vh.z)), hhw = bf2f(f2bf(vh.w));
        Ahi32[bg2]     = pack2(vg.x, vg.y);
        Ahi32[bg2 + 1] = pack2(vg.z, vg.w);
        Alo32[bg2]     = pack2(vg.x - ghx, vg.y - ghy);
        Alo32[bg2 + 1] = pack2(vg.z - ghz, vg.w - ghw);
        Ahi32[bh2]     = pack2(vh.x, vh.y);
        Ahi32[bh2 + 1] = pack2(vh.z, vh.w);
        Alo32[bh2]     = pack2(vh.x - hhx, vh.y - hhy);
        Alo32[bh2 + 1] = pack2(vh.z - hhz, vh.w - hhw);
    }
    __syncthreads();

    int lane  = t & 63;
    int w     = t >> 6;              // wave = j-group
    int l15   = lane & 15;
    int kbase = (lane >> 4) * 8;     // K sub-block per mfma fragment

    f32x4 acc[4][4];
#pragma unroll
    for (int a = 0; a < 4; ++a)
#pragma unroll
        for (int m = 0; m < 4; ++m) acc[a][m] = (f32x4){0.f, 0.f, 0.f, 0.f};

#pragma unroll
    for (int g = 0; g < 3; ++g) {
        int brow = (w + 4 * g) * 16 + l15;
        short8 bh[4], bl[4];
#pragma unroll
        for (int ks = 0; ks < 4; ++ks) {
            bh[ks] = *(const short8*)(Bhi + brow * 128 + ks * 32 + kbase);
            bl[ks] = *(const short8*)(Blo + brow * 128 + ks * 32 + kbase);
        }
#pragma unroll
        for (int mt = 0; mt < 4; ++mt) {
            int abase = (mt * 16 + l15) * 136 + kbase;
#pragma unroll
            for (int ks = 0; ks < 4; ++ks) {
                short8 ah = *(const short8*)&Ahi[abase + ks * 32];
                short8 al = *(const short8*)&Alo[abase + ks * 32];
                acc[g][mt] = __builtin_amdgcn_mfma_f32_16x16x32_bf16(ah, bh[ks], acc[g][mt], 0, 0, 0);
                acc[g][mt] = __builtin_amdgcn_mfma_f32_16x16x32_bf16(al, bh[ks], acc[g][mt], 0, 0, 0);
                acc[g][mt] = __builtin_amdgcn_mfma_f32_16x16x32_bf16(ah, bl[ks], acc[g][mt], 0, 0, 0);
            }
        }
    }
    {
        int brow = w * 16 + l15;
        short8 bh[2], bl[2];
#pragma unroll
        for (int ks = 0; ks < 2; ++ks) {
            bh[ks] = *(const short8*)(BShi + brow * 64 + ks * 32 + kbase);
            bl[ks] = *(const short8*)(BSlo + brow * 64 + ks * 32 + kbase);
        }
#pragma unroll
        for (int mt = 0; mt < 4; ++mt) {
            int abase = (mt * 16 + l15) * 136 + 64 + kbase;
#pragma unroll
            for (int ks = 0; ks < 2; ++ks) {
                short8 ah = *(const short8*)&Ahi[abase + ks * 32];
                short8 al = *(const short8*)&Alo[abase + ks * 32];
                acc[3][mt] = __builtin_amdgcn_mfma_f32_16x16x32_bf16(ah, bh[ks], acc[3][mt], 0, 0, 0);
                acc[3][mt] = __builtin_amdgcn_mfma_f32_16x16x32_bf16(al, bh[ks], acc[3][mt], 0, 0, 0);
                acc[3][mt] = __builtin_amdgcn_mfma_f32_16x16x32_bf16(ah, bl[ks], acc[3][mt], 0, 0, 0);
            }
        }
    }

    int j = 16 * w + l15;
    float br  = bih[j] + bhh[j];
    float bz  = bih[HH + j] + bhh[HH + j];
    float bin = bih[2 * HH + j];
    float bhn = bhh[2 * HH + j];
#pragma unroll
    for (int mt = 0; mt < 4; ++mt) {
#pragma unroll
        for (int reg = 0; reg < 4; ++reg) {
            int row  = mt * 16 + (lane >> 4) * 4 + reg;
            int node = n0 + row;
            if (node < NN) {
                float S1 = acc[0][mt][reg];
                float S2 = acc[1][mt][reg];
                float S3 = acc[2][mt][reg];   // i_n + h_n
                float Hn = acc[3][mt][reg];   // h_n
                float r  = __builtin_amdgcn_rcpf(1.f + __expf(-(S1 + br)));
                float z  = __builtin_amdgcn_rcpf(1.f + __expf(-(S2 + bz)));
                float na = (S3 - Hn + bin) + r * (Hn + bhn);
                float e2 = __expf(2.f * na);
                float nv = fmaf(-2.f, __builtin_amdgcn_rcpf(1.f + e2), 1.f);  // tanh
                int lidx = row * 136 + 64 + j;
                float h  = bf2f(Ahi[lidx]) + bf2f(Alo[lidx]);  // hprev
                float o  = (1.f - z) * nv + z * h;
                out[(size_t)node * HH + j] = o;
                out[(size_t)NN * HH + (size_t)node * HH + j] = o;
            }
        }
    }
}

extern "C" void kernel_launch(void* const* d_in, const int* in_sizes, int n_in,
                              void* d_out, int out_size, void* d_ws, size_t ws_size,
                              hipStream_t stream) {
    const float* x   = (const float*)d_in[0];
    const int*   ei  = (const int*)d_in[1];
    const float* hs  = (const float*)d_in[2];
    const float* Wg  = (const float*)d_in[3];
    const float* bg  = (const float*)d_in[4];
    const float* Wih = (const float*)d_in[5];
    const float* Whh = (const float*)d_in[6];
    const float* bih = (const float*)d_in[7];
    const float* bhh = (const float*)d_in[8];
    float* out = (float*)d_out;

    char* ws = (char*)d_ws;
    // epoch 1: pairs (16.02 MB) at 0 — dead after k_csr
    // epoch 2: xtb (12.8 MB bf16) at 0 (written by k_xt, after k_csr)
    int*    pairs  = (int*)   (ws);                // 391*10240*4 = 16,015,360 B
    ushort* xtb    = (ushort*)(ws);                // 12,800,000 B (after k_csr)
    float*  gbuf   = (float*) (ws + 16400000);     // 25,600,000 B
    int*    csr    = (int*)   (ws + 42000000);     // 12,800,000 B
    int*    deg    = (int*)   (ws + 54800000);     //    400,000 B
    int*    rowptr = (int*)   (ws + 55200000);     //    400,000 B
    float*  dis    = (float*) (ws + 55600000);     //    400,000 B
    ushort* wsplit = (ushort*)(ws + 56000000);     //    147,456 B
    int*    gcnt   = (int*)   (ws + 56200000);     //      2,048 B

    hipLaunchKernelGGL(k_wprep, dim3(96), dim3(256), 0, stream, Wih, Whh, Wg, wsplit, gcnt);
    hipLaunchKernelGGL(k_part,  dim3((NE + 8191) / 8192), dim3(256), 0, stream, ei, gcnt, pairs);
    hipLaunchKernelGGL(k_csr,   dim3(NFB), dim3(512), 0, stream,
                       pairs, gcnt, deg, rowptr, dis, csr);
    hipLaunchKernelGGL(k_xt,    dim3((NN + 63) / 64), dim3(256), 0, stream,
                       x, wsplit + 2 * 192 * 128 + 2 * 64 * 64, dis, xtb);
    hipLaunchKernelGGL(k_gather, dim3(NN / 4), dim3(256), 0, stream,
                       csr, rowptr, deg, dis, xtb, bg, gbuf);
    hipLaunchKernelGGL(k_gru,   dim3((NN + 63) / 64), dim3(256), 0, stream,
                       gbuf, hs, wsplit, bih, bhh, out);
}